// Round 1
// 813.713 us; speedup vs baseline: 1.0617x; 1.0617x over previous
//
#include <hip/hip_runtime.h>

// Inverse 2x2 Haar synthesis (IWT).
// Input  x: [B=8, 4*C=256, H=256, W=256] fp32, subband order LL,LH,HL,HH (C=64 each)
// Output o: [B=8, C=64, 2H=512, 2W=512] fp32
// out[b,c,2h+p,2w+q] = 0.25 * (LL +/- LH +/- HL +/- HH) per Haar signs.
//
// Memory-bound: 512 MiB in + 512 MiB out, zero reuse. Design goals:
//  - every global instruction fully lane-contiguous:
//      loads : float2/lane  -> 64*8B  = 512B contiguous per wave instr
//      stores: float4/lane  -> 64*16B = 1KiB contiguous per wave instr
//    (previous version stored 16B at 32B lane stride: half-filled 64B lines
//     per instruction, relying on L2 write-merge)
//  - nontemporal (nt) on all traffic: 1 GiB streams through L2/L3 with no
//    reuse; don't thrash the caches.

#define B_ 8
#define C_ 64
#define H_ 256
#define W_ 256

typedef float f32x2 __attribute__((ext_vector_type(2)));
typedef float f32x4 __attribute__((ext_vector_type(4)));

__global__ __launch_bounds__(256) void iwt_kernel(const float* __restrict__ x,
                                                  float* __restrict__ out) {
    // One thread handles 2 consecutive input w -> 4 consecutive output cols.
    // total threads = 8*64*256*128 = 16,777,216
    const int tid = blockIdx.x * 256 + threadIdx.x;
    const int w2 = tid & 127;           // w/2 (128 pairs along W)
    const int h  = (tid >> 7) & 255;
    const int c  = (tid >> 15) & 63;
    const int b  = tid >> 21;

    const int HW      = H_ * W_;             // 65536
    const int kstride = C_ * HW;             // 4,194,304 (one subband block)
    const int in_base = b * (4 * kstride) + c * HW + h * W_ + (w2 << 1);

    const f32x2 ll = __builtin_nontemporal_load((const f32x2*)(x + in_base));
    const f32x2 lh = __builtin_nontemporal_load((const f32x2*)(x + in_base + kstride));
    const f32x2 hl = __builtin_nontemporal_load((const f32x2*)(x + in_base + 2 * kstride));
    const f32x2 hh = __builtin_nontemporal_load((const f32x2*)(x + in_base + 3 * kstride));

    // out(0,0)=(LL+LH+HL+HH)/4  out(0,1)=(LL+LH-HL-HH)/4
    // out(1,0)=(LL-LH+HL-HH)/4  out(1,1)=(LL-LH-HL+HH)/4
    f32x4 r0, r1;
    float u, v, p, q;
#define HAAR1(A, Bv, Cv, D, O00, O01, O10, O11)        \
    u = (A) + (Bv); v = (A) - (Bv);                    \
    p = (Cv) + (D); q = (Cv) - (D);                    \
    O00 = (u + p) * 0.25f; O01 = (u - p) * 0.25f;      \
    O10 = (v + q) * 0.25f; O11 = (v - q) * 0.25f;

    HAAR1(ll.x, lh.x, hl.x, hh.x, r0.x, r0.y, r1.x, r1.y)
    HAAR1(ll.y, lh.y, hl.y, hh.y, r0.z, r0.w, r1.z, r1.w)
#undef HAAR1

    // Output: [B, C, 512, 512]; rows 2h and 2h+1, columns 4*w2 .. 4*w2+3
    // Lane i of a wave -> byte offset 16*i within a 1 KiB span: fully coalesced.
    const int out_row0 = ((b * C_ + c) * (2 * H_) + 2 * h) * (2 * W_) + (w2 << 2);
    __builtin_nontemporal_store(r0, (f32x4*)(out + out_row0));
    __builtin_nontemporal_store(r1, (f32x4*)(out + out_row0 + 2 * W_));
}

extern "C" void kernel_launch(void* const* d_in, const int* in_sizes, int n_in,
                              void* d_out, int out_size, void* d_ws, size_t ws_size,
                              hipStream_t stream) {
    const float* x = (const float*)d_in[0];
    float* out = (float*)d_out;
    const int total_threads = B_ * C_ * H_ * (W_ / 2);   // 16,777,216
    const int block = 256;
    const int grid = total_threads / block;              // 65536
    iwt_kernel<<<grid, block, 0, stream>>>(x, out);
}